// Round 8
// baseline (229.194 us; speedup 1.0000x reference)
//
#include <hip/hip_runtime.h>
#include <math.h>

// PinSAGE fused pipeline, r8: occupancy-first. W in LDS (XOR-swizzled),
// barrier-free per-wave 16-row tile streams, 16 waves/CU on k1.
// D=U=E=128, T=20 fixed; N, V from in_sizes.
//
// K0 prep:  WqT/WnT/WwT/WgT = bf16 transpose of weights (WT[n][k])
// K1:       H = relu(table @ Wn + bn) -> bf16 [V][128]     (blocks < splitH)
//           nodeh = relu(table[node_ids] @ Wq + bq) -> nh[:,0:128] (rest)
//           W 32 KB LDS; 1024 blocks, lb(256,4) -> 4 blocks/CU.
// K2 agg:   nh[:,128:256] = sum_t alpha * H[neigh]  (gather-FMA)
// K3 emb:   embb = relu(nh @ Ww + bw) bf16 + sumsq partials; K=256,
//           W 64 KB LDS, wave-tiles, 512 blocks.
// K4 final: out = relu(scale*(embb @ Wg) + bg) fp32; scale from inline
//           reduction of partials; W 32 KB LDS, wave-tiles, 782 blocks.
//
// MFMA orientation (verified r3..r7): acc[mt] = mfma(wfrag, afrag, acc) ->
// lane l holds C[row = tile*16 + (l&15)][cols 16*mt + 4*(l>>4) + i].

using f32x4  = __attribute__((ext_vector_type(4))) float;
using short8 = __attribute__((ext_vector_type(8))) short;   // 8 bf16

__device__ __forceinline__ ushort f2bf(float f) {
    uint u = __float_as_uint(f);
    return (ushort)((u + 0x7fffu + ((u >> 16) & 1u)) >> 16);   // RNE
}
__device__ __forceinline__ float bf2f(ushort h) {
    return __uint_as_float((uint)h << 16);
}
__device__ __forceinline__ uint pk2(float lo, float hi) {
    return (uint)f2bf(lo) | ((uint)f2bf(hi) << 16);
}
__device__ __forceinline__ short8 pack8(f32x4 a, f32x4 b) {
    uint4 r;
    r.x = pk2(a[0], a[1]); r.y = pk2(a[2], a[3]);
    r.z = pk2(b[0], b[1]); r.w = pk2(b[2], b[3]);
    union { uint4 u; short8 s; } cv; cv.u = r; return cv.s;
}

// ---------------------------------------------------------------------------
__global__ __launch_bounds__(256)
void prep_weights(const float* __restrict__ Wq, const float* __restrict__ Wn,
                  const float* __restrict__ Ww, const float* __restrict__ Wg,
                  ushort* __restrict__ WqT, ushort* __restrict__ WnT,
                  ushort* __restrict__ WwT, ushort* __restrict__ WgT)
{
    int idx = blockIdx.x * 256 + threadIdx.x;   // 320 blocks -> 81920
    const float* W; ushort* WT; int K; int j = idx;
    if (j < 16384)      { W = Wq; WT = WqT; K = 128; }
    else if (j < 32768) { W = Wn; WT = WnT; K = 128; j -= 16384; }
    else if (j < 65536) { W = Ww; WT = WwT; K = 256; j -= 32768; }
    else                { W = Wg; WT = WgT; K = 128; j -= 65536; }
    int n = j & 127, k = j >> 7;
    WT[(size_t)n * K + k] = f2bf(W[j]);
}

// ---------------------------------------------------------------------------
// W staging + fragment read (XOR-swizzled: byte ^= (n&7)<<4 within row)
// ---------------------------------------------------------------------------
__device__ __forceinline__ void stage_w128(const ushort* __restrict__ WT,
                                           ushort* Wlds, int tid)
{
#pragma unroll
    for (int it = 0; it < 8; ++it) {
        int idx = it * 256 + tid, n = idx >> 4, o = idx & 15;
        uint4 v = *reinterpret_cast<const uint4*>(&WT[(size_t)n * 128 + 8 * o]);
        *reinterpret_cast<uint4*>((char*)Wlds + n * 256 + ((16 * o) ^ ((n & 7) << 4))) = v;
    }
}
__device__ __forceinline__ void stage_w256(const ushort* __restrict__ WT,
                                           ushort* Wlds, int tid)
{
#pragma unroll
    for (int it = 0; it < 16; ++it) {
        int idx = it * 256 + tid, n = idx >> 5, o = idx & 31;
        uint4 v = *reinterpret_cast<const uint4*>(&WT[(size_t)n * 256 + 8 * o]);
        *reinterpret_cast<uint4*>((char*)Wlds + n * 512 + ((16 * o) ^ ((n & 7) << 4))) = v;
    }
}
__device__ __forceinline__ short8 ldw(const ushort* Wlds, int rowbytes,
                                      int mt, int ks, int l16, int lh)
{
    return *reinterpret_cast<const short8*>(
        (const char*)Wlds + (16 * mt + l16) * rowbytes +
        ((64 * ks + 16 * lh) ^ ((l16 & 7) << 4)));
}

// ---------------------------------------------------------------------------
// K1: dual GEMM, W in LDS, barrier-free per-wave 16-row tiles, prefetch-1.
// ---------------------------------------------------------------------------
__global__ __launch_bounds__(256, 4)
void k1_w(const float* __restrict__ table, const int* __restrict__ node_ids,
          const ushort* __restrict__ WnT, const float* __restrict__ bn,
          const ushort* __restrict__ WqT, const float* __restrict__ bq,
          ushort* __restrict__ H, ushort* __restrict__ nh,
          int V, int N, int splitH)
{
    __shared__ __align__(16) ushort Wlds[128 * 128];   // 32 KB
    __shared__ __align__(16) float blds[128];
    const int tid = threadIdx.x;
    const int w = tid >> 6, l = tid & 63, l16 = l & 15, lh = l >> 4;
    const bool isH = (int)blockIdx.x < splitH;

    stage_w128(isH ? WnT : WqT, Wlds, tid);
    if (tid < 128) blds[tid] = (isH ? bn : bq)[tid];
    __syncthreads();

    const int M   = isH ? V : N;
    ushort* out   = isH ? H : nh;
    const int ldo = isH ? 128 : 256;
    const int nt  = (M + 15) >> 4;
    const int wid    = (isH ? (int)blockIdx.x : (int)blockIdx.x - splitH) * 4 + w;
    const int nwaves = (isH ? splitH : (int)gridDim.x - splitH) * 4;

    f32x4 f[8];
    if (wid < nt) {                     // prologue loads for first tile
        const int row = wid * 16 + l16;
        int g = (row < M) ? row : (M - 1);
        if (!isH) g = node_ids[g];
        const float* rp = table + (size_t)g * 128 + 8 * lh;
#pragma unroll
        for (int ks = 0; ks < 4; ++ks) {
            f[2 * ks]     = *reinterpret_cast<const f32x4*>(rp + 32 * ks);
            f[2 * ks + 1] = *reinterpret_cast<const f32x4*>(rp + 32 * ks + 4);
        }
    }

    for (int tile = wid; tile < nt; tile += nwaves) {
        short8 a[4];                    // pack current (waits in-flight loads)
#pragma unroll
        for (int ks = 0; ks < 4; ++ks) a[ks] = pack8(f[2 * ks], f[2 * ks + 1]);

        const int nxt = tile + nwaves;  // prefetch next tile
        if (nxt < nt) {
            const int row = nxt * 16 + l16;
            int g = (row < M) ? row : (M - 1);
            if (!isH) g = node_ids[g];
            const float* rp = table + (size_t)g * 128 + 8 * lh;
#pragma unroll
            for (int ks = 0; ks < 4; ++ks) {
                f[2 * ks]     = *reinterpret_cast<const f32x4*>(rp + 32 * ks);
                f[2 * ks + 1] = *reinterpret_cast<const f32x4*>(rp + 32 * ks + 4);
            }
        }

        f32x4 acc[8];
#pragma unroll
        for (int mt = 0; mt < 8; ++mt)
#pragma unroll
            for (int i = 0; i < 4; ++i) acc[mt][i] = 0.f;
#pragma unroll
        for (int ks = 0; ks < 4; ++ks)
#pragma unroll
            for (int mt = 0; mt < 8; ++mt)
                acc[mt] = __builtin_amdgcn_mfma_f32_16x16x32_bf16(
                    ldw(Wlds, 256, mt, ks, l16, lh), a[ks], acc[mt], 0, 0, 0);

        const int row = tile * 16 + l16;
        if (row < M) {
#pragma unroll
            for (int mt = 0; mt < 8; ++mt) {
                f32x4 bv = *reinterpret_cast<const f32x4*>(&blds[16 * mt + 4 * lh]);
                uint2 q;
                q.x = pk2(fmaxf(acc[mt][0] + bv[0], 0.f), fmaxf(acc[mt][1] + bv[1], 0.f));
                q.y = pk2(fmaxf(acc[mt][2] + bv[2], 0.f), fmaxf(acc[mt][3] + bv[3], 0.f));
                *reinterpret_cast<uint2*>(&out[(size_t)row * ldo + 16 * mt + 4 * lh]) = q;
            }
        }
    }
}

// ---------------------------------------------------------------------------
// K2: agg[n][:] = sum_t alpha[n,t] * H[neigh_ids[n,t]][:]
// ---------------------------------------------------------------------------
__global__ __launch_bounds__(256)
void agg_bf16(const ushort* __restrict__ H,
              const int* __restrict__ nids,
              const float* __restrict__ alpha,
              ushort* __restrict__ outb,     // nh + 128, row stride 256
              int N)
{
    const int n   = blockIdx.x * 16 + (threadIdx.x >> 4);
    const int l16 = threadIdx.x & 15;
    if (n >= N) return;

    const int*   idp = &nids[n * 20];
    const float* alp = &alpha[n * 20];
    float a[8];
#pragma unroll
    for (int j = 0; j < 8; ++j) a[j] = 0.f;
#pragma unroll
    for (int t = 0; t < 20; ++t) {
        const int   id = idp[t];
        const float al = alp[t];
        uint4 h = *reinterpret_cast<const uint4*>(&H[(size_t)id * 128 + 8 * l16]);
        a[0] = fmaf(al, bf2f((ushort)(h.x & 0xffff)), a[0]);
        a[1] = fmaf(al, bf2f((ushort)(h.x >> 16)),    a[1]);
        a[2] = fmaf(al, bf2f((ushort)(h.y & 0xffff)), a[2]);
        a[3] = fmaf(al, bf2f((ushort)(h.y >> 16)),    a[3]);
        a[4] = fmaf(al, bf2f((ushort)(h.z & 0xffff)), a[4]);
        a[5] = fmaf(al, bf2f((ushort)(h.z >> 16)),    a[5]);
        a[6] = fmaf(al, bf2f((ushort)(h.w & 0xffff)), a[6]);
        a[7] = fmaf(al, bf2f((ushort)(h.w >> 16)),    a[7]);
    }
    uint4 p;
    p.x = pk2(a[0], a[1]); p.y = pk2(a[2], a[3]);
    p.z = pk2(a[4], a[5]); p.w = pk2(a[6], a[7]);
    *reinterpret_cast<uint4*>(&outb[(size_t)n * 256 + 8 * l16]) = p;
}

// ---------------------------------------------------------------------------
// K3: emb = relu(nh @ Ww + bw) -> bf16 embb + per-block sumsq. K=256,
// W 64 KB LDS, barrier-free wave tiles, block reduction at the end.
// ---------------------------------------------------------------------------
__global__ __launch_bounds__(256, 2)
void k3_emb(const ushort* __restrict__ nh, const ushort* __restrict__ WwT,
            const float* __restrict__ bw, ushort* __restrict__ embb,
            float* __restrict__ partials, int N)
{
    __shared__ __align__(16) ushort Wlds[128 * 256];   // 64 KB
    __shared__ __align__(16) float blds[128];
    __shared__ float red[256];
    const int tid = threadIdx.x;
    const int w = tid >> 6, l = tid & 63, l16 = l & 15, lh = l >> 4;

    stage_w256(WwT, Wlds, tid);
    if (tid < 128) blds[tid] = bw[tid];
    __syncthreads();

    const int nt = (N + 15) >> 4;
    const int wid = (int)blockIdx.x * 4 + w;
    const int nwaves = (int)gridDim.x * 4;
    float ssq = 0.f;

    short8 a[8];
    if (wid < nt) {
        const int row = wid * 16 + l16;
        const int g = (row < N) ? row : (N - 1);
        const ushort* rp = nh + (size_t)g * 256 + 8 * lh;
#pragma unroll
        for (int ks = 0; ks < 8; ++ks)
            a[ks] = *reinterpret_cast<const short8*>(rp + 32 * ks);
    }

    for (int tile = wid; tile < nt; tile += nwaves) {
        short8 cur[8];
#pragma unroll
        for (int ks = 0; ks < 8; ++ks) cur[ks] = a[ks];

        const int nxt = tile + nwaves;
        if (nxt < nt) {
            const int row = nxt * 16 + l16;
            const int g = (row < N) ? row : (N - 1);
            const ushort* rp = nh + (size_t)g * 256 + 8 * lh;
#pragma unroll
            for (int ks = 0; ks < 8; ++ks)
                a[ks] = *reinterpret_cast<const short8*>(rp + 32 * ks);
        }

        f32x4 acc[8];
#pragma unroll
        for (int mt = 0; mt < 8; ++mt)
#pragma unroll
            for (int i = 0; i < 4; ++i) acc[mt][i] = 0.f;
#pragma unroll
        for (int ks = 0; ks < 8; ++ks)
#pragma unroll
            for (int mt = 0; mt < 8; ++mt)
                acc[mt] = __builtin_amdgcn_mfma_f32_16x16x32_bf16(
                    ldw(Wlds, 512, mt, ks, l16, lh), cur[ks], acc[mt], 0, 0, 0);

        const int row = tile * 16 + l16;
        const bool ok = row < N;
#pragma unroll
        for (int mt = 0; mt < 8; ++mt) {
            f32x4 bv = *reinterpret_cast<const f32x4*>(&blds[16 * mt + 4 * lh]);
            f32x4 v;
#pragma unroll
            for (int i = 0; i < 4; ++i) v[i] = fmaxf(acc[mt][i] + bv[i], 0.f);
            if (ok) {
                ssq += v[0] * v[0] + v[1] * v[1] + v[2] * v[2] + v[3] * v[3];
                uint2 q; q.x = pk2(v[0], v[1]); q.y = pk2(v[2], v[3]);
                *reinterpret_cast<uint2*>(&embb[(size_t)row * 128 + 16 * mt + 4 * lh]) = q;
            }
        }
    }

    red[tid] = ssq;
    __syncthreads();
    for (int st = 128; st > 0; st >>= 1) {
        if (tid < st) red[tid] += red[tid + st];
        __syncthreads();
    }
    if (tid == 0) partials[blockIdx.x] = red[0];
}

// ---------------------------------------------------------------------------
// K4: out = relu(scale*(embb @ Wg) + bg) fp32; scale reduced inline.
// W 32 KB LDS, barrier-free wave tiles.
// ---------------------------------------------------------------------------
__global__ __launch_bounds__(256, 4)
void k4_final(const ushort* __restrict__ embb, const ushort* __restrict__ WgT,
              const float* __restrict__ bg, const float* __restrict__ partials,
              int P, float* __restrict__ outp, int N)
{
    __shared__ __align__(16) ushort Wlds[128 * 128];   // 32 KB
    __shared__ __align__(16) float blds[128];
    __shared__ float red[256];
    __shared__ float s_scale;
    const int tid = threadIdx.x;
    const int w = tid >> 6, l = tid & 63, l16 = l & 15, lh = l >> 4;

    stage_w128(WgT, Wlds, tid);
    if (tid < 128) blds[tid] = bg[tid];
    float s = 0.f;
    for (int i = tid; i < P; i += 256) s += partials[i];
    red[tid] = s;
    __syncthreads();
    for (int st = 128; st > 0; st >>= 1) {
        if (tid < st) red[tid] += red[tid + st];
        __syncthreads();
    }
    if (tid == 0) s_scale = 1.0f / sqrtf(red[0]);
    __syncthreads();
    const float scale = s_scale;

    const int nt = (N + 15) >> 4;
    const int wid = (int)blockIdx.x * 4 + w;
    const int nwaves = (int)gridDim.x * 4;

    short8 a[4];
    if (wid < nt) {
        const int row = wid * 16 + l16;
        const int g = (row < N) ? row : (N - 1);
        const ushort* rp = embb + (size_t)g * 128 + 8 * lh;
#pragma unroll
        for (int ks = 0; ks < 4; ++ks)
            a[ks] = *reinterpret_cast<const short8*>(rp + 32 * ks);
    }

    for (int tile = wid; tile < nt; tile += nwaves) {
        short8 cur[4];
#pragma unroll
        for (int ks = 0; ks < 4; ++ks) cur[ks] = a[ks];

        const int nxt = tile + nwaves;
        if (nxt < nt) {
            const int row = nxt * 16 + l16;
            const int g = (row < N) ? row : (N - 1);
            const ushort* rp = embb + (size_t)g * 128 + 8 * lh;
#pragma unroll
            for (int ks = 0; ks < 4; ++ks)
                a[ks] = *reinterpret_cast<const short8*>(rp + 32 * ks);
        }

        f32x4 acc[8];
#pragma unroll
        for (int mt = 0; mt < 8; ++mt)
#pragma unroll
            for (int i = 0; i < 4; ++i) acc[mt][i] = 0.f;
#pragma unroll
        for (int ks = 0; ks < 4; ++ks)
#pragma unroll
            for (int mt = 0; mt < 8; ++mt)
                acc[mt] = __builtin_amdgcn_mfma_f32_16x16x32_bf16(
                    ldw(Wlds, 256, mt, ks, l16, lh), cur[ks], acc[mt], 0, 0, 0);

        const int row = tile * 16 + l16;
        if (row < N) {
#pragma unroll
            for (int mt = 0; mt < 8; ++mt) {
                f32x4 bv = *reinterpret_cast<const f32x4*>(&blds[16 * mt + 4 * lh]);
                f32x4 v;
#pragma unroll
                for (int i = 0; i < 4; ++i)
                    v[i] = fmaxf(fmaf(acc[mt][i], scale, bv[i]), 0.f);
                *reinterpret_cast<f32x4*>(&outp[(size_t)row * 128 + 16 * mt + 4 * lh]) = v;
            }
        }
    }
}

// ---------------------------------------------------------------------------
extern "C" void kernel_launch(void* const* d_in, const int* in_sizes, int n_in,
                              void* d_out, int out_size, void* d_ws, size_t ws_size,
                              hipStream_t stream)
{
    const int*   node_ids  = (const int*)  d_in[0];
    const int*   neigh_ids = (const int*)  d_in[1];
    const float* alpha     = (const float*)d_in[2];
    const float* table     = (const float*)d_in[3];
    const float* Wq        = (const float*)d_in[4];
    const float* bq        = (const float*)d_in[5];
    const float* Wn        = (const float*)d_in[6];
    const float* bn        = (const float*)d_in[7];
    const float* Ww        = (const float*)d_in[8];
    const float* bw        = (const float*)d_in[9];
    const float* Wg        = (const float*)d_in[10];
    const float* bg        = (const float*)d_in[11];

    const int N = in_sizes[0];            // 50000
    const int V = in_sizes[3] / 128;      // 200000
    float* out = (float*)d_out;

    // workspace layout
    ushort* H    = (ushort*)d_ws;                 // [V][128] bf16
    ushort* nh   = H    + (size_t)V * 128;        // [N][256] = [node_h | agg]
    ushort* embb = nh   + (size_t)N * 256;        // [N][128]
    ushort* WqT  = embb + (size_t)N * 128;
    ushort* WnT  = WqT  + 16384;
    ushort* WwT  = WnT  + 16384;
    ushort* WgT  = WwT  + 32768;
    float*  partials = (float*)(WgT + 16384);     // 1024
    float*  scale    = partials + 1024;

    const size_t need = (size_t)((char*)(scale + 16) - (char*)d_ws);
    if (ws_size < need) return;

    // K1 grid: 1024 blocks (4/CU), split by 16-row tile counts
    const int G1 = 1024;
    const long long tH = (V + 15) / 16, tN = (N + 15) / 16;
    int splitH = (int)((G1 * tH) / (tH + tN));
    if (splitH < 1) splitH = 1;
    if (splitH > G1 - 1) splitH = G1 - 1;

    const int G3 = 512;
    const int ntN = (N + 15) / 16;
    int G4 = (ntN + 3) / 4;               // one tile per wave in a single pass
    if (G4 > 2048) G4 = 2048;

    prep_weights<<<320, 256, 0, stream>>>(Wq, Wn, Ww, Wg, WqT, WnT, WwT, WgT);
    k1_w<<<G1, 256, 0, stream>>>(table, node_ids, WnT, bn, WqT, bq,
                                 H, nh, V, N, splitH);
    agg_bf16<<<(N + 15) / 16, 256, 0, stream>>>(H, neigh_ids, alpha, nh + 128, N);
    k3_emb<<<G3, 256, 0, stream>>>(nh, WwT, bw, embb, partials, N);
    k4_final<<<G4, 256, 0, stream>>>(embb, WgT, bg, partials, G3, out, N);
}

// Round 9
// 138.327 us; speedup vs baseline: 1.6569x; 1.6569x over previous
//
#include <hip/hip_runtime.h>
#include <math.h>

// PinSAGE fused pipeline, r9: r8 structure with the register-cap bug fixed.
// All GEMMs use lb(256,2) (VGPR cap 128, no spills); occupancy comes from
// actual resource use: 33 KB LDS -> 4 blocks/CU -> 16 waves/CU on k1/k4.
// D=U=E=128, T=20 fixed; N, V from in_sizes.
//
// K0 prep:  WqT/WnT/WwT/WgT = bf16 transpose of weights (WT[n][k])
// K1:       H = relu(table @ Wn + bn) -> bf16 [V][128]     (blocks < splitH)
//           nodeh = relu(table[node_ids] @ Wq + bq) -> nh[:,0:128] (rest)
//           W 32 KB LDS (XOR-swizzled); barrier-free per-wave 16-row tiles,
//           1-deep register prefetch; grid 2048.
// K2 agg:   nh[:,128:256] = sum_t alpha * H[neigh]  (gather-FMA)
// K3 emb:   embb = relu(nh @ Ww + bw) bf16 + sumsq partials; K=256,
//           W 64 KB LDS, wave-tiles, 512 blocks.
// K4 final: out = relu(scale*(embb @ Wg) + bg) fp32; inline partials reduce;
//           W 32 KB LDS, wave-tiles, 1024 blocks.
//
// MFMA orientation (verified r3..r8): acc[mt] = mfma(wfrag, afrag, acc) ->
// lane l holds C[row = tile*16 + (l&15)][cols 16*mt + 4*(l>>4) + i].

using f32x4  = __attribute__((ext_vector_type(4))) float;
using short8 = __attribute__((ext_vector_type(8))) short;   // 8 bf16

__device__ __forceinline__ ushort f2bf(float f) {
    uint u = __float_as_uint(f);
    return (ushort)((u + 0x7fffu + ((u >> 16) & 1u)) >> 16);   // RNE
}
__device__ __forceinline__ float bf2f(ushort h) {
    return __uint_as_float((uint)h << 16);
}
__device__ __forceinline__ uint pk2(float lo, float hi) {
    return (uint)f2bf(lo) | ((uint)f2bf(hi) << 16);
}
__device__ __forceinline__ short8 pack8(f32x4 a, f32x4 b) {
    uint4 r;
    r.x = pk2(a[0], a[1]); r.y = pk2(a[2], a[3]);
    r.z = pk2(b[0], b[1]); r.w = pk2(b[2], b[3]);
    union { uint4 u; short8 s; } cv; cv.u = r; return cv.s;
}

// ---------------------------------------------------------------------------
__global__ __launch_bounds__(256)
void prep_weights(const float* __restrict__ Wq, const float* __restrict__ Wn,
                  const float* __restrict__ Ww, const float* __restrict__ Wg,
                  ushort* __restrict__ WqT, ushort* __restrict__ WnT,
                  ushort* __restrict__ WwT, ushort* __restrict__ WgT)
{
    int idx = blockIdx.x * 256 + threadIdx.x;   // 320 blocks -> 81920
    const float* W; ushort* WT; int K; int j = idx;
    if (j < 16384)      { W = Wq; WT = WqT; K = 128; }
    else if (j < 32768) { W = Wn; WT = WnT; K = 128; j -= 16384; }
    else if (j < 65536) { W = Ww; WT = WwT; K = 256; j -= 32768; }
    else                { W = Wg; WT = WgT; K = 128; j -= 65536; }
    int n = j & 127, k = j >> 7;
    WT[(size_t)n * K + k] = f2bf(W[j]);
}

// ---------------------------------------------------------------------------
// W staging + fragment read (XOR-swizzled: byte ^= (n&7)<<4 within row)
// ---------------------------------------------------------------------------
__device__ __forceinline__ void stage_w128(const ushort* __restrict__ WT,
                                           ushort* Wlds, int tid)
{
#pragma unroll
    for (int it = 0; it < 8; ++it) {
        int idx = it * 256 + tid, n = idx >> 4, o = idx & 15;
        uint4 v = *reinterpret_cast<const uint4*>(&WT[(size_t)n * 128 + 8 * o]);
        *reinterpret_cast<uint4*>((char*)Wlds + n * 256 + ((16 * o) ^ ((n & 7) << 4))) = v;
    }
}
__device__ __forceinline__ void stage_w256(const ushort* __restrict__ WT,
                                           ushort* Wlds, int tid)
{
#pragma unroll
    for (int it = 0; it < 16; ++it) {
        int idx = it * 256 + tid, n = idx >> 5, o = idx & 31;
        uint4 v = *reinterpret_cast<const uint4*>(&WT[(size_t)n * 256 + 8 * o]);
        *reinterpret_cast<uint4*>((char*)Wlds + n * 512 + ((16 * o) ^ ((n & 7) << 4))) = v;
    }
}
__device__ __forceinline__ short8 ldw(const ushort* Wlds, int rowbytes,
                                      int mt, int ks, int l16, int lh)
{
    return *reinterpret_cast<const short8*>(
        (const char*)Wlds + (16 * mt + l16) * rowbytes +
        ((64 * ks + 16 * lh) ^ ((l16 & 7) << 4)));
}

// ---------------------------------------------------------------------------
// K1: dual GEMM, W in LDS, barrier-free per-wave 16-row tiles, prefetch-1.
// lb(256,2): compiler free up to 128 VGPR; HW co-schedules 4 blocks/CU
// (LDS 33 KB) when VGPR <= 128 -> 16 waves/CU.
// ---------------------------------------------------------------------------
__global__ __launch_bounds__(256, 2)
void k1_w(const float* __restrict__ table, const int* __restrict__ node_ids,
          const ushort* __restrict__ WnT, const float* __restrict__ bn,
          const ushort* __restrict__ WqT, const float* __restrict__ bq,
          ushort* __restrict__ H, ushort* __restrict__ nh,
          int V, int N, int splitH)
{
    __shared__ __align__(16) ushort Wlds[128 * 128];   // 32 KB
    __shared__ __align__(16) float blds[128];
    const int tid = threadIdx.x;
    const int w = tid >> 6, l = tid & 63, l16 = l & 15, lh = l >> 4;
    const bool isH = (int)blockIdx.x < splitH;

    stage_w128(isH ? WnT : WqT, Wlds, tid);
    if (tid < 128) blds[tid] = (isH ? bn : bq)[tid];
    __syncthreads();

    const int M   = isH ? V : N;
    ushort* out   = isH ? H : nh;
    const int ldo = isH ? 128 : 256;
    const int nt  = (M + 15) >> 4;
    const int wid    = (isH ? (int)blockIdx.x : (int)blockIdx.x - splitH) * 4 + w;
    const int nwaves = (isH ? splitH : (int)gridDim.x - splitH) * 4;

    f32x4 f[8];
    if (wid < nt) {                     // prologue loads for first tile
        const int row = wid * 16 + l16;
        int g = (row < M) ? row : (M - 1);
        if (!isH) g = node_ids[g];
        const float* rp = table + (size_t)g * 128 + 8 * lh;
#pragma unroll
        for (int ks = 0; ks < 4; ++ks) {
            f[2 * ks]     = *reinterpret_cast<const f32x4*>(rp + 32 * ks);
            f[2 * ks + 1] = *reinterpret_cast<const f32x4*>(rp + 32 * ks + 4);
        }
    }

    for (int tile = wid; tile < nt; tile += nwaves) {
        short8 a[4];                    // pack current (waits in-flight loads)
#pragma unroll
        for (int ks = 0; ks < 4; ++ks) a[ks] = pack8(f[2 * ks], f[2 * ks + 1]);

        const int nxt = tile + nwaves;  // prefetch next tile
        if (nxt < nt) {
            const int row = nxt * 16 + l16;
            int g = (row < M) ? row : (M - 1);
            if (!isH) g = node_ids[g];
            const float* rp = table + (size_t)g * 128 + 8 * lh;
#pragma unroll
            for (int ks = 0; ks < 4; ++ks) {
                f[2 * ks]     = *reinterpret_cast<const f32x4*>(rp + 32 * ks);
                f[2 * ks + 1] = *reinterpret_cast<const f32x4*>(rp + 32 * ks + 4);
            }
        }

        f32x4 acc[8];
#pragma unroll
        for (int mt = 0; mt < 8; ++mt)
#pragma unroll
            for (int i = 0; i < 4; ++i) acc[mt][i] = 0.f;
#pragma unroll
        for (int ks = 0; ks < 4; ++ks)
#pragma unroll
            for (int mt = 0; mt < 8; ++mt)
                acc[mt] = __builtin_amdgcn_mfma_f32_16x16x32_bf16(
                    ldw(Wlds, 256, mt, ks, l16, lh), a[ks], acc[mt], 0, 0, 0);

        const int row = tile * 16 + l16;
        if (row < M) {
#pragma unroll
            for (int mt = 0; mt < 8; ++mt) {
                f32x4 bv = *reinterpret_cast<const f32x4*>(&blds[16 * mt + 4 * lh]);
                uint2 q;
                q.x = pk2(fmaxf(acc[mt][0] + bv[0], 0.f), fmaxf(acc[mt][1] + bv[1], 0.f));
                q.y = pk2(fmaxf(acc[mt][2] + bv[2], 0.f), fmaxf(acc[mt][3] + bv[3], 0.f));
                *reinterpret_cast<uint2*>(&out[(size_t)row * ldo + 16 * mt + 4 * lh]) = q;
            }
        }
    }
}

// ---------------------------------------------------------------------------
// K2: agg[n][:] = sum_t alpha[n,t] * H[neigh_ids[n,t]][:]
// ---------------------------------------------------------------------------
__global__ __launch_bounds__(256)
void agg_bf16(const ushort* __restrict__ H,
              const int* __restrict__ nids,
              const float* __restrict__ alpha,
              ushort* __restrict__ outb,     // nh + 128, row stride 256
              int N)
{
    const int n   = blockIdx.x * 16 + (threadIdx.x >> 4);
    const int l16 = threadIdx.x & 15;
    if (n >= N) return;

    const int*   idp = &nids[n * 20];
    const float* alp = &alpha[n * 20];
    float a[8];
#pragma unroll
    for (int j = 0; j < 8; ++j) a[j] = 0.f;
#pragma unroll
    for (int t = 0; t < 20; ++t) {
        const int   id = idp[t];
        const float al = alp[t];
        uint4 h = *reinterpret_cast<const uint4*>(&H[(size_t)id * 128 + 8 * l16]);
        a[0] = fmaf(al, bf2f((ushort)(h.x & 0xffff)), a[0]);
        a[1] = fmaf(al, bf2f((ushort)(h.x >> 16)),    a[1]);
        a[2] = fmaf(al, bf2f((ushort)(h.y & 0xffff)), a[2]);
        a[3] = fmaf(al, bf2f((ushort)(h.y >> 16)),    a[3]);
        a[4] = fmaf(al, bf2f((ushort)(h.z & 0xffff)), a[4]);
        a[5] = fmaf(al, bf2f((ushort)(h.z >> 16)),    a[5]);
        a[6] = fmaf(al, bf2f((ushort)(h.w & 0xffff)), a[6]);
        a[7] = fmaf(al, bf2f((ushort)(h.w >> 16)),    a[7]);
    }
    uint4 p;
    p.x = pk2(a[0], a[1]); p.y = pk2(a[2], a[3]);
    p.z = pk2(a[4], a[5]); p.w = pk2(a[6], a[7]);
    *reinterpret_cast<uint4*>(&outb[(size_t)n * 256 + 8 * l16]) = p;
}

// ---------------------------------------------------------------------------
// K3: emb = relu(nh @ Ww + bw) -> bf16 embb + per-block sumsq. K=256,
// W 64 KB LDS, barrier-free wave tiles.
// ---------------------------------------------------------------------------
__global__ __launch_bounds__(256, 2)
void k3_emb(const ushort* __restrict__ nh, const ushort* __restrict__ WwT,
            const float* __restrict__ bw, ushort* __restrict__ embb,
            float* __restrict__ partials, int N)
{
    __shared__ __align__(16) ushort Wlds[128 * 256];   // 64 KB
    __shared__ __align__(16) float blds[128];
    __shared__ float red[256];
    const int tid = threadIdx.x;
    const int w = tid >> 6, l = tid & 63, l16 = l & 15, lh = l >> 4;

    stage_w256(WwT, Wlds, tid);
    if (tid < 128) blds[tid] = bw[tid];
    __syncthreads();

    const int nt = (N + 15) >> 4;
    const int wid = (int)blockIdx.x * 4 + w;
    const int nwaves = (int)gridDim.x * 4;
    float ssq = 0.f;

    short8 a[8];
    if (wid < nt) {
        const int row = wid * 16 + l16;
        const int g = (row < N) ? row : (N - 1);
        const ushort* rp = nh + (size_t)g * 256 + 8 * lh;
#pragma unroll
        for (int ks = 0; ks < 8; ++ks)
            a[ks] = *reinterpret_cast<const short8*>(rp + 32 * ks);
    }

    for (int tile = wid; tile < nt; tile += nwaves) {
        short8 cur[8];
#pragma unroll
        for (int ks = 0; ks < 8; ++ks) cur[ks] = a[ks];

        const int nxt = tile + nwaves;
        if (nxt < nt) {
            const int row = nxt * 16 + l16;
            const int g = (row < N) ? row : (N - 1);
            const ushort* rp = nh + (size_t)g * 256 + 8 * lh;
#pragma unroll
            for (int ks = 0; ks < 8; ++ks)
                a[ks] = *reinterpret_cast<const short8*>(rp + 32 * ks);
        }

        f32x4 acc[8];
#pragma unroll
        for (int mt = 0; mt < 8; ++mt)
#pragma unroll
            for (int i = 0; i < 4; ++i) acc[mt][i] = 0.f;
#pragma unroll
        for (int ks = 0; ks < 8; ++ks)
#pragma unroll
            for (int mt = 0; mt < 8; ++mt)
                acc[mt] = __builtin_amdgcn_mfma_f32_16x16x32_bf16(
                    ldw(Wlds, 512, mt, ks, l16, lh), cur[ks], acc[mt], 0, 0, 0);

        const int row = tile * 16 + l16;
        const bool ok = row < N;
#pragma unroll
        for (int mt = 0; mt < 8; ++mt) {
            f32x4 bv = *reinterpret_cast<const f32x4*>(&blds[16 * mt + 4 * lh]);
            f32x4 v;
#pragma unroll
            for (int i = 0; i < 4; ++i) v[i] = fmaxf(acc[mt][i] + bv[i], 0.f);
            if (ok) {
                ssq += v[0] * v[0] + v[1] * v[1] + v[2] * v[2] + v[3] * v[3];
                uint2 q; q.x = pk2(v[0], v[1]); q.y = pk2(v[2], v[3]);
                *reinterpret_cast<uint2*>(&embb[(size_t)row * 128 + 16 * mt + 4 * lh]) = q;
            }
        }
    }

    red[tid] = ssq;
    __syncthreads();
    for (int st = 128; st > 0; st >>= 1) {
        if (tid < st) red[tid] += red[tid + st];
        __syncthreads();
    }
    if (tid == 0) partials[blockIdx.x] = red[0];
}

// ---------------------------------------------------------------------------
// K4: out = relu(scale*(embb @ Wg) + bg) fp32; scale reduced inline.
// W 32 KB LDS, barrier-free wave tiles, lb(256,2).
// ---------------------------------------------------------------------------
__global__ __launch_bounds__(256, 2)
void k4_final(const ushort* __restrict__ embb, const ushort* __restrict__ WgT,
              const float* __restrict__ bg, const float* __restrict__ partials,
              int P, float* __restrict__ outp, int N)
{
    __shared__ __align__(16) ushort Wlds[128 * 128];   // 32 KB
    __shared__ __align__(16) float blds[128];
    __shared__ float red[256];
    __shared__ float s_scale;
    const int tid = threadIdx.x;
    const int w = tid >> 6, l = tid & 63, l16 = l & 15, lh = l >> 4;

    stage_w128(WgT, Wlds, tid);
    if (tid < 128) blds[tid] = bg[tid];
    float s = 0.f;
    for (int i = tid; i < P; i += 256) s += partials[i];
    red[tid] = s;
    __syncthreads();
    for (int st = 128; st > 0; st >>= 1) {
        if (tid < st) red[tid] += red[tid + st];
        __syncthreads();
    }
    if (tid == 0) s_scale = 1.0f / sqrtf(red[0]);
    __syncthreads();
    const float scale = s_scale;

    const int nt = (N + 15) >> 4;
    const int wid = (int)blockIdx.x * 4 + w;
    const int nwaves = (int)gridDim.x * 4;

    short8 a[4];
    if (wid < nt) {
        const int row = wid * 16 + l16;
        const int g = (row < N) ? row : (N - 1);
        const ushort* rp = embb + (size_t)g * 128 + 8 * lh;
#pragma unroll
        for (int ks = 0; ks < 4; ++ks)
            a[ks] = *reinterpret_cast<const short8*>(rp + 32 * ks);
    }

    for (int tile = wid; tile < nt; tile += nwaves) {
        short8 cur[4];
#pragma unroll
        for (int ks = 0; ks < 4; ++ks) cur[ks] = a[ks];

        const int nxt = tile + nwaves;
        if (nxt < nt) {
            const int row = nxt * 16 + l16;
            const int g = (row < N) ? row : (N - 1);
            const ushort* rp = embb + (size_t)g * 128 + 8 * lh;
#pragma unroll
            for (int ks = 0; ks < 4; ++ks)
                a[ks] = *reinterpret_cast<const short8*>(rp + 32 * ks);
        }

        f32x4 acc[8];
#pragma unroll
        for (int mt = 0; mt < 8; ++mt)
#pragma unroll
            for (int i = 0; i < 4; ++i) acc[mt][i] = 0.f;
#pragma unroll
        for (int ks = 0; ks < 4; ++ks)
#pragma unroll
            for (int mt = 0; mt < 8; ++mt)
                acc[mt] = __builtin_amdgcn_mfma_f32_16x16x32_bf16(
                    ldw(Wlds, 256, mt, ks, l16, lh), cur[ks], acc[mt], 0, 0, 0);

        const int row = tile * 16 + l16;
        if (row < N) {
#pragma unroll
            for (int mt = 0; mt < 8; ++mt) {
                f32x4 bv = *reinterpret_cast<const f32x4*>(&blds[16 * mt + 4 * lh]);
                f32x4 v;
#pragma unroll
                for (int i = 0; i < 4; ++i)
                    v[i] = fmaxf(fmaf(acc[mt][i], scale, bv[i]), 0.f);
                *reinterpret_cast<f32x4*>(&outp[(size_t)row * 128 + 16 * mt + 4 * lh]) = v;
            }
        }
    }
}

// ---------------------------------------------------------------------------
extern "C" void kernel_launch(void* const* d_in, const int* in_sizes, int n_in,
                              void* d_out, int out_size, void* d_ws, size_t ws_size,
                              hipStream_t stream)
{
    const int*   node_ids  = (const int*)  d_in[0];
    const int*   neigh_ids = (const int*)  d_in[1];
    const float* alpha     = (const float*)d_in[2];
    const float* table     = (const float*)d_in[3];
    const float* Wq        = (const float*)d_in[4];
    const float* bq        = (const float*)d_in[5];
    const float* Wn        = (const float*)d_in[6];
    const float* bn        = (const float*)d_in[7];
    const float* Ww        = (const float*)d_in[8];
    const float* bw        = (const float*)d_in[9];
    const float* Wg        = (const float*)d_in[10];
    const float* bg        = (const float*)d_in[11];

    const int N = in_sizes[0];            // 50000
    const int V = in_sizes[3] / 128;      // 200000
    float* out = (float*)d_out;

    // workspace layout
    ushort* H    = (ushort*)d_ws;                 // [V][128] bf16
    ushort* nh   = H    + (size_t)V * 128;        // [N][256] = [node_h | agg]
    ushort* embb = nh   + (size_t)N * 256;        // [N][128]
    ushort* WqT  = embb + (size_t)N * 128;
    ushort* WnT  = WqT  + 16384;
    ushort* WwT  = WnT  + 16384;
    ushort* WgT  = WwT  + 32768;
    float*  partials = (float*)(WgT + 16384);     // 1024
    float*  scale    = partials + 1024;

    const size_t need = (size_t)((char*)(scale + 16) - (char*)d_ws);
    if (ws_size < need) return;

    // K1 grid: 2048 blocks, split by 16-row tile counts
    const int G1 = 2048;
    const long long tH = (V + 15) / 16, tN = (N + 15) / 16;
    int splitH = (int)((G1 * tH) / (tH + tN));
    if (splitH < 1) splitH = 1;
    if (splitH > G1 - 1) splitH = G1 - 1;

    const int G3 = 512;
    const int G4 = 1024;

    prep_weights<<<320, 256, 0, stream>>>(Wq, Wn, Ww, Wg, WqT, WnT, WwT, WgT);
    k1_w<<<G1, 256, 0, stream>>>(table, node_ids, WnT, bn, WqT, bq,
                                 H, nh, V, N, splitH);
    agg_bf16<<<(N + 15) / 16, 256, 0, stream>>>(H, neigh_ids, alpha, nh + 128, N);
    k3_emb<<<G3, 256, 0, stream>>>(nh, WwT, bw, embb, partials, N);
    k4_final<<<G4, 256, 0, stream>>>(embb, WgT, bg, partials, G3, out, N);
}